// Round 4
// baseline (424.226 us; speedup 1.0000x reference)
//
#include <hip/hip_runtime.h>

// Cost-volume builder:
// out[b, c2, d, h, w] with shape (4, 64, 48, 64, 128) fp32
//   c2 <  32: (w >= d) ? left [b, c2,    h, w    ] : 0
//   c2 >= 32: (w >= d) ? right[b, c2-32, h, w - d] : 0
//
// R4: amortize per-wave overhead. R1/R3 did one 16 B store per thread
// (98,304 tiny blocks) and ran at only ~2.4 TB/s effective write BW while
// harness fills hit 6.3 TB/s. Now: one block = one (bc,d) plane (32 KB
// contiguous), 8 float4 nt-stores per thread, 12,288 blocks.
// Mask (w>=d) is k-invariant per thread -> computed once, applied via select.

#define BB 4
#define CC 32
#define HH 64
#define WW 128
#define DD 48

typedef float vfloat4 __attribute__((ext_vector_type(4)));

__global__ __launch_bounds__(256) void cost_kernel(
    const float* __restrict__ left,
    const float* __restrict__ right,
    float* __restrict__ out)
{
    const int tid = threadIdx.x;
    const int d   = blockIdx.x;          // 0..47
    const int bc  = blockIdx.y;          // 0..255 = b*64 + c2
    const int b   = bc >> 6;
    const int c2  = bc & 63;
    const int h0  = tid >> 5;            // 0..7
    const int w0  = (tid & 31) * 4;      // 0,4,...,124

    const bool is_right = (c2 >= CC);    // uniform per block
    const int  c        = is_right ? (c2 - CC) : c2;
    const float* __restrict__ plane =
        (is_right ? right : left) + (((size_t)b * CC + c) * HH) * WW;

    vfloat4* __restrict__ out4 = reinterpret_cast<vfloat4*>(out)
                               + ((size_t)bc * DD + d) * (HH * WW / 4);

    // per-thread mask, invariant across k
    const bool m0 = (w0 + 0) >= d;
    const bool m1 = (w0 + 1) >= d;
    const bool m2 = (w0 + 2) >= d;
    const bool m3 = (w0 + 3) >= d;

    if (!is_right) {
        #pragma unroll
        for (int k = 0; k < 8; ++k) {
            const int h = h0 + 8 * k;
            vfloat4 v = *reinterpret_cast<const vfloat4*>(plane + h * WW + w0);
            v.x = m0 ? v.x : 0.0f;
            v.y = m1 ? v.y : 0.0f;
            v.z = m2 ? v.z : 0.0f;
            v.w = m3 ? v.w : 0.0f;
            __builtin_nontemporal_store(v, out4 + k * 256 + tid);
        }
    } else {
        // clamped branch-free gather at w-d; masked lanes read index 0 harmlessly
        const int s0 = max(w0 + 0 - d, 0);
        const int s1 = max(w0 + 1 - d, 0);
        const int s2 = max(w0 + 2 - d, 0);
        const int s3 = max(w0 + 3 - d, 0);
        #pragma unroll
        for (int k = 0; k < 8; ++k) {
            const float* __restrict__ row = plane + (h0 + 8 * k) * WW;
            vfloat4 v;
            v.x = m0 ? row[s0] : 0.0f;
            v.y = m1 ? row[s1] : 0.0f;
            v.z = m2 ? row[s2] : 0.0f;
            v.w = m3 ? row[s3] : 0.0f;
            __builtin_nontemporal_store(v, out4 + k * 256 + tid);
        }
    }
}

extern "C" void kernel_launch(void* const* d_in, const int* in_sizes, int n_in,
                              void* d_out, int out_size, void* d_ws, size_t ws_size,
                              hipStream_t stream)
{
    const float* left  = (const float*)d_in[0];
    const float* right = (const float*)d_in[1];
    float* out = (float*)d_out;

    dim3 grid(DD, BB * 2 * CC);          // (48, 256) = 12,288 blocks
    cost_kernel<<<grid, dim3(256), 0, stream>>>(left, right, out);
}